// Round 14
// baseline (98.087 us; speedup 1.0000x reference)
//
#include <hip/hip_runtime.h>
#include <hip/hip_fp16.h>

// FixedPointLSTMCell on MI355X — R14: R13 schedule + 32x32x16 MFMA core.
// Same FLOP, half the MFMA instruction count (32 vs 64 per wave-K-step),
// 15% higher MFMA ceiling (m119: 2495 vs 2176 TF), identical LDS read volume.
// n-frag == gate n (wrows n*32..+31, col = lane&31) -> fused epilogue stays
// in-thread. C/D: col=lane&31, row=(reg&3)+8*(reg>>2)+4*(lane>>5) [m74/m101].
// Numerics (== R12/R13, absmax 0.031 < 0.094 thr): operands integer at scale
// 2^8, f16 MFMA exact (fp32 accum < 2^24); both biases folded into acc seed;
// single rounding s = rint(acc/256) (<=1 LSB vs ref's two roundings).

typedef _Float16 half8 __attribute__((ext_vector_type(8)));
typedef float f32x16 __attribute__((ext_vector_type(16)));

#define AS1 __attribute__((address_space(1)))
#define AS3 __attribute__((address_space(3)))

__device__ __forceinline__ void gload16(const void* g, void* l) {
  __builtin_amdgcn_global_load_lds((const AS1 void*)g, (AS3 void*)l, 16, 0, 0);
}

__device__ __forceinline__ float quant256(float v) {
  float q = rintf(v * 256.0f);
  return fminf(fmaxf(q, -32767.0f), 32767.0f);
}

// ---------------- prep: quantize inputs to integer-valued fp16 ----------------
__global__ __launch_bounds__(256) void prep_kernel(
    const float* __restrict__ x, const float* __restrict__ h,
    const float* __restrict__ Wi, const float* __restrict__ Wh,
    const float* __restrict__ bi, const float* __restrict__ bh,
    __half* __restrict__ xq, __half* __restrict__ hq,
    __half* __restrict__ wiq, __half* __restrict__ whq,
    float* __restrict__ biq, float* __restrict__ bhq) {
  const int i = blockIdx.x * 256 + threadIdx.x;  // 4 elems each
  {
    const float4 vx = ((const float4*)x)[i];
    const float4 vh = ((const float4*)h)[i];
    union { __half hh[4]; uint2 u; } ux, uh;
    ux.hh[0] = __half(quant256(vx.x)); ux.hh[1] = __half(quant256(vx.y));
    ux.hh[2] = __half(quant256(vx.z)); ux.hh[3] = __half(quant256(vx.w));
    uh.hh[0] = __half(quant256(vh.x)); uh.hh[1] = __half(quant256(vh.y));
    uh.hh[2] = __half(quant256(vh.z)); uh.hh[3] = __half(quant256(vh.w));
    ((uint2*)xq)[i] = ux.u;
    ((uint2*)hq)[i] = uh.u;
  }
  if (i < 262144) {  // weights: 2048*512/4
    const float4 vi4 = ((const float4*)Wi)[i];
    const float4 vh4 = ((const float4*)Wh)[i];
    union { __half hh[4]; uint2 u; } uwi, uwh;
    uwi.hh[0] = __half(quant256(vi4.x)); uwi.hh[1] = __half(quant256(vi4.y));
    uwi.hh[2] = __half(quant256(vi4.z)); uwi.hh[3] = __half(quant256(vi4.w));
    uwh.hh[0] = __half(quant256(vh4.x)); uwh.hh[1] = __half(quant256(vh4.y));
    uwh.hh[2] = __half(quant256(vh4.z)); uwh.hh[3] = __half(quant256(vh4.w));
    ((uint2*)wiq)[i] = uwi.u;
    ((uint2*)whq)[i] = uwh.u;
  }
  if (i < 512) {  // biases (scaled-int, as float)
    #pragma unroll
    for (int j = 0; j < 4; ++j) {
      biq[i * 4 + j] = quant256(bi[i * 4 + j]);
      bhq[i * 4 + j] = quant256(bh[i * 4 + j]);
    }
  }
}

// ---------------- two-phase gate-fused GEMM + LSTM cell ----------------
// Block: 256 threads (4 waves), BM=256 rows, col-tile = 32 h-cols x 4 gates
// (128 gate-major wrows). Wave wid: rows [wid*64,+64): m=2 frags of 32 rows;
// n=4 frags, frag n == gate n (wrow = n*32 + (lane&31)) -> fused epilogue.
// Superloop T=0..15: tiles 0-7 X@Wi^T, 8-15 H@Wh^T (single acc, both biases
// pre-seeded). Per ITER: [W(T) DMA][A(T+1) DMA][vmcnt(8)][bar][32 MFMA][bar].
__global__ __launch_bounds__(256, 2) void lstm_gemm(
    const __half* __restrict__ xq, const __half* __restrict__ hq,
    const __half* __restrict__ wiq, const __half* __restrict__ whq,
    const float* __restrict__ biq, const float* __restrict__ bhq,
    const float* __restrict__ cprev,
    float* __restrict__ out_h, float* __restrict__ out_c) {
  __shared__ __align__(16) __half sA[2][256 * 64];  // 64 KB (A dbuf)
  __shared__ __align__(16) __half sW[128 * 64];     // 16 KB (W single)

  const int tid = threadIdx.x;
  const int lane = tid & 63;
  const int wid = tid >> 6;     // 0..3: 64-row slab
  const int l31 = lane & 31;
  const int lh = lane >> 5;     // k-half within a K=16 slice

  // XCD-aware bijective swizzle (1024 % 8 == 0)
  const int bid = blockIdx.x;
  const int lbid = (bid & 7) * 128 + (bid >> 3);
  const int tileM = lbid >> 4;  // 0..63
  const int tileN = lbid & 15;  // 0..15
  const int row0 = tileM * 256;
  const int col0 = tileN * 32;

  f32x16 acc[2][4];

  // hoisted loop-invariant staging offsets (element units; only kk varies)
  int ainv[8], winv[4];
  {
    const int b = lane & 7;
    const int lr = lane >> 3;
    #pragma unroll
    for (int i2 = 0; i2 < 8; ++i2) {
      const int r = (wid * 8 + i2) * 8 + lr;
      ainv[i2] = (row0 + r) * 512 + ((b ^ (r & 7)) << 3);
    }
    #pragma unroll
    for (int i2 = 0; i2 < 4; ++i2) {
      const int r = (wid * 4 + i2) * 8 + lr;
      const int gr = (r >> 5) * 512 + col0 + (r & 31);  // gate-major wrow
      winv[i2] = gr * 512 + ((b ^ (r & 7)) << 3);
    }
  }

  // seed acc with (bi + bh)*256 — frag n = gate n, col = col0 + l31
  #pragma unroll
  for (int n = 0; n < 4; ++n) {
    const int gwr = n * 512 + col0 + l31;
    const float b256 = (biq[gwr] + bhq[gwr]) * 256.0f;
    #pragma unroll
    for (int m = 0; m < 2; ++m)
      #pragma unroll
      for (int r = 0; r < 16; ++r) acc[m][n][r] = b256;
  }

  #define STAGE_A(Asrc, kkv, dst)                                             \
    {                                                                         \
      _Pragma("unroll")                                                       \
      for (int i2 = 0; i2 < 8; ++i2)                                          \
        gload16((Asrc) + ainv[i2] + (kkv),                                    \
                (char*)&sA[dst][0] + (wid * 8 + i2) * 1024);                  \
    }
  #define STAGE_W(Wsrc, kkv)                                                  \
    {                                                                         \
      _Pragma("unroll")                                                       \
      for (int i2 = 0; i2 < 4; ++i2)                                          \
        gload16((Wsrc) + winv[i2] + (kkv),                                    \
                (char*)sW + (wid * 4 + i2) * 1024);                           \
    }
  // 32x32x16 core: 4 K=16 slices per K-step; per slice 2 av + 4 bv reads,
  // 8 MFMA. Per-lane A/B: row/wrow = lane&31, k-half = lane>>5.
  #define COMPUTE(cur)                                                        \
    {                                                                         \
      _Pragma("unroll")                                                       \
      for (int ksl = 0; ksl < 4; ++ksl) {                                     \
        const int kb = ksl * 2 + lh;                                          \
        half8 av[2];                                                          \
        _Pragma("unroll")                                                     \
        for (int m = 0; m < 2; ++m) {                                         \
          const int r = wid * 64 + m * 32 + l31;                              \
          av[m] = *(const half8*)&sA[cur][r * 64 + ((kb ^ (r & 7)) << 3)];    \
        }                                                                     \
        half8 bv[4];                                                          \
        _Pragma("unroll")                                                     \
        for (int n = 0; n < 4; ++n) {                                         \
          const int wr = n * 32 + l31;                                        \
          bv[n] = *(const half8*)&sW[wr * 64 + ((kb ^ (wr & 7)) << 3)];       \
        }                                                                     \
        __builtin_amdgcn_s_setprio(1);                                        \
        _Pragma("unroll")                                                     \
        for (int n = 0; n < 4; ++n)                                           \
          _Pragma("unroll")                                                   \
          for (int m = 0; m < 2; ++m)                                         \
            acc[m][n] = __builtin_amdgcn_mfma_f32_32x32x16_f16(               \
                av[m], bv[n], acc[m][n], 0, 0, 0);                            \
        __builtin_amdgcn_s_setprio(0);                                        \
      }                                                                       \
    }

  // ITER(T): W(T) DMA; A(T+1) DMA into buf (T+1)&1; vmcnt(8) [A(T),W(T) done,
  // A(T+1) in flight]; barrier; compute on buf T&1; barrier.
  #define ITER(T)                                                             \
    {                                                                         \
      { const __half* Wp_ = ((T) < 8) ? wiq : whq;                            \
        STAGE_W(Wp_, ((T) & 7) * 64) }                                        \
      if ((T) < 15) {                                                         \
        const __half* An_ = (((T) + 1) < 8) ? xq : hq;                        \
        STAGE_A(An_, (((T) + 1) & 7) * 64, ((T) + 1) & 1)                     \
      }                                                                       \
      if ((T) < 15) { asm volatile("s_waitcnt vmcnt(8)" ::: "memory"); }      \
      else          { asm volatile("s_waitcnt vmcnt(0)" ::: "memory"); }      \
      __builtin_amdgcn_sched_barrier(0);                                      \
      __builtin_amdgcn_s_barrier();                                           \
      COMPUTE((T) & 1)                                                        \
      __builtin_amdgcn_s_barrier();                                           \
    }

  // prologue: A(0) -> sA[0] (completed at ITER(0)'s vmcnt)
  STAGE_A(xq, 0, 0)

  ITER(0)  ITER(1)  ITER(2)  ITER(3)
  ITER(4)  ITER(5)  ITER(6)  ITER(7)
  ITER(8)  ITER(9)  ITER(10) ITER(11)
  ITER(12) ITER(13) ITER(14) ITER(15)

  #undef ITER
  #undef COMPUTE
  #undef STAGE_A
  #undef STAGE_W

  // ---- final epilogue: s = rint(acc/256); gates -> c, h ----
  // C/D layout: col = lane&31, row = (reg&3) + 8*(reg>>2) + 4*(lane>>5)
  #pragma unroll
  for (int m = 0; m < 2; ++m)
    #pragma unroll
    for (int rg = 0; rg < 16; ++rg) {
      float s[4];
      #pragma unroll
      for (int g = 0; g < 4; ++g)
        s[g] = rintf(acc[m][g][rg] * (1.0f / 256.0f));  // pre-act * 256 (int)
      float vi, vf, vo, gg;
      {
        float t0 = (s[0] * (1.0f / 256.0f)) / 6.0f + 0.5f;
        vi = rintf(fminf(fmaxf(t0, 0.0f), 1.0f) * 256.0f);
      }
      {
        float t1 = (s[1] * (1.0f / 256.0f)) / 6.0f + 0.5f;
        vf = rintf(fminf(fmaxf(t1, 0.0f), 1.0f) * 256.0f);
      }
      gg = fminf(fmaxf(s[2], -256.f), 256.f);  // hard_tanh + quant == clip
      {
        float t3 = (s[3] * (1.0f / 256.0f)) / 6.0f + 0.5f;
        vo = rintf(fminf(fmaxf(t3, 0.0f), 1.0f) * 256.0f);
      }
      const int R = row0 + wid * 64 + m * 32 + (rg & 3) + 8 * (rg >> 2) + 4 * lh;
      const int C = col0 + l31;
      const float cpq = quant256(cprev[R * 512 + C]);
      const float cnum = vf * cpq + vi * gg;       // exact int, scale 2^16
      const float cval = cnum * (1.0f / 65536.0f);
      out_c[R * 512 + C] = cval;
      const float tt = fminf(fmaxf(cval, -1.0f), 1.0f);
      const float th = rintf(tt * 256.0f);
      out_h[R * 512 + C] = (vo * th) * (1.0f / 65536.0f);
    }
}

extern "C" void kernel_launch(void* const* d_in, const int* in_sizes, int n_in,
                              void* d_out, int out_size, void* d_ws, size_t ws_size,
                              hipStream_t stream) {
  const float* x      = (const float*)d_in[0];
  const float* h_prev = (const float*)d_in[1];
  const float* c_prev = (const float*)d_in[2];
  const float* W_ih   = (const float*)d_in[3];
  const float* b_ih   = (const float*)d_in[4];
  const float* W_hh   = (const float*)d_in[5];
  const float* b_hh   = (const float*)d_in[6];
  float* out = (float*)d_out;

  char* ws = (char*)d_ws;
  __half* xqp  = (__half*)(ws);
  __half* hqp  = (__half*)(ws + (16u << 20));
  __half* wiqp = (__half*)(ws + (32u << 20));
  __half* whqp = (__half*)(ws + (34u << 20));
  float*  biqp = (float*)(ws + (36u << 20));
  float*  bhqp = (float*)(ws + (36u << 20) + 8192);

  prep_kernel<<<8192, 256, 0, stream>>>(x, h_prev, W_ih, W_hh, b_ih, b_hh,
                                        xqp, hqp, wiqp, whqp, biqp, bhqp);

  lstm_gemm<<<1024, 256, 0, stream>>>(xqp, hqp, wiqp, whqp, biqp, bhqp,
                                      c_prev, out, out + 8388608);
}

// Round 15
// 89.981 us; speedup vs baseline: 1.0901x; 1.0901x over previous
//
#include <hip/hip_runtime.h>
#include <hip/hip_fp16.h>

// FixedPointLSTMCell on MI355X — R15: R13 (best, 87.5us) + cprev LDS prefetch.
// R14's 32x32 core reverted: 32-lane/32-row fragment reads are inherently
// 4-way bank-conflicted at row-stride 128B (6.29M conflict cycles measured).
// New: at ITER(15), sA[0] is dead -> DMA the 256x32 cprev tile into it
// (overlapped with the last K-step); epilogue reads cprev from LDS, removing
// ~500-900cy of exposed global latency per block tail.
// Numerics (== R12/R13, absmax 0.031 < 0.094 thr): operands integer at scale
// 2^8, f16 MFMA exact (fp32 accum < 2^24); both biases folded into acc seed;
// single rounding s = rint(acc/256) (<=1 LSB vs ref's two roundings).

typedef _Float16 half8 __attribute__((ext_vector_type(8)));
typedef float f32x4 __attribute__((ext_vector_type(4)));

#define AS1 __attribute__((address_space(1)))
#define AS3 __attribute__((address_space(3)))

__device__ __forceinline__ void gload16(const void* g, void* l) {
  __builtin_amdgcn_global_load_lds((const AS1 void*)g, (AS3 void*)l, 16, 0, 0);
}

__device__ __forceinline__ float quant256(float v) {
  float q = rintf(v * 256.0f);
  return fminf(fmaxf(q, -32767.0f), 32767.0f);
}

// ---------------- prep: quantize inputs to integer-valued fp16 ----------------
__global__ __launch_bounds__(256) void prep_kernel(
    const float* __restrict__ x, const float* __restrict__ h,
    const float* __restrict__ Wi, const float* __restrict__ Wh,
    const float* __restrict__ bi, const float* __restrict__ bh,
    __half* __restrict__ xq, __half* __restrict__ hq,
    __half* __restrict__ wiq, __half* __restrict__ whq,
    float* __restrict__ biq, float* __restrict__ bhq) {
  const int i = blockIdx.x * 256 + threadIdx.x;  // 4 elems each
  {
    const float4 vx = ((const float4*)x)[i];
    const float4 vh = ((const float4*)h)[i];
    union { __half hh[4]; uint2 u; } ux, uh;
    ux.hh[0] = __half(quant256(vx.x)); ux.hh[1] = __half(quant256(vx.y));
    ux.hh[2] = __half(quant256(vx.z)); ux.hh[3] = __half(quant256(vx.w));
    uh.hh[0] = __half(quant256(vh.x)); uh.hh[1] = __half(quant256(vh.y));
    uh.hh[2] = __half(quant256(vh.z)); uh.hh[3] = __half(quant256(vh.w));
    ((uint2*)xq)[i] = ux.u;
    ((uint2*)hq)[i] = uh.u;
  }
  if (i < 262144) {  // weights: 2048*512/4
    const float4 vi4 = ((const float4*)Wi)[i];
    const float4 vh4 = ((const float4*)Wh)[i];
    union { __half hh[4]; uint2 u; } uwi, uwh;
    uwi.hh[0] = __half(quant256(vi4.x)); uwi.hh[1] = __half(quant256(vi4.y));
    uwi.hh[2] = __half(quant256(vi4.z)); uwi.hh[3] = __half(quant256(vi4.w));
    uwh.hh[0] = __half(quant256(vh4.x)); uwh.hh[1] = __half(quant256(vh4.y));
    uwh.hh[2] = __half(quant256(vh4.z)); uwh.hh[3] = __half(quant256(vh4.w));
    ((uint2*)wiq)[i] = uwi.u;
    ((uint2*)whq)[i] = uwh.u;
  }
  if (i < 512) {  // biases (scaled-int, as float)
    #pragma unroll
    for (int j = 0; j < 4; ++j) {
      biq[i * 4 + j] = quant256(bi[i * 4 + j]);
      bhq[i * 4 + j] = quant256(bh[i * 4 + j]);
    }
  }
}

// ---------------- two-phase gate-fused GEMM + LSTM cell ----------------
// Block: 256 threads (4 waves), BM=256 rows, col-tile = 32 h-cols x 4 gates
// (128 gate-major wrows). Wave wid: rows [wid*64,+64), m=4; n=8 frags span
// all 128 wrows (frag n = gate n>>1, col (n&1)*16+l15) -> fused epilogue.
// Superloop T=0..15: tiles 0-7 X@Wi^T, 8-15 H@Wh^T (single acc, both biases
// pre-seeded). Per ITER: [W(T) DMA][A(T+1) DMA][vmcnt(8)][bar][64 MFMA][bar].
// ITER(15) stages cprev into the dead sA[0] instead of an A tile.
__global__ __launch_bounds__(256, 2) void lstm_gemm(
    const __half* __restrict__ xq, const __half* __restrict__ hq,
    const __half* __restrict__ wiq, const __half* __restrict__ whq,
    const float* __restrict__ biq, const float* __restrict__ bhq,
    const float* __restrict__ cprev,
    float* __restrict__ out_h, float* __restrict__ out_c) {
  __shared__ __align__(16) __half sA[2][256 * 64];  // 64 KB (A dbuf)
  __shared__ __align__(16) __half sW[128 * 64];     // 16 KB (W single)

  const int tid = threadIdx.x;
  const int lane = tid & 63;
  const int wid = tid >> 6;     // 0..3: 64-row slab
  const int l15 = lane & 15;
  const int l4 = lane >> 4;

  // XCD-aware bijective swizzle (1024 % 8 == 0)
  const int bid = blockIdx.x;
  const int lbid = (bid & 7) * 128 + (bid >> 3);
  const int tileM = lbid >> 4;  // 0..63
  const int tileN = lbid & 15;  // 0..15
  const int row0 = tileM * 256;
  const int col0 = tileN * 32;

  f32x4 acc[4][8];

  // hoisted loop-invariant staging offsets (element units; only kk varies)
  int ainv[8], winv[4];
  {
    const int b = lane & 7;
    const int lr = lane >> 3;
    #pragma unroll
    for (int i2 = 0; i2 < 8; ++i2) {
      const int r = (wid * 8 + i2) * 8 + lr;
      ainv[i2] = (row0 + r) * 512 + ((b ^ (r & 7)) << 3);
    }
    #pragma unroll
    for (int i2 = 0; i2 < 4; ++i2) {
      const int r = (wid * 4 + i2) * 8 + lr;
      const int gr = (r >> 5) * 512 + col0 + (r & 31);  // gate-major wrow
      winv[i2] = gr * 512 + ((b ^ (r & 7)) << 3);
    }
  }

  // seed acc with (bi + bh)*256 — both biases folded before single rounding
  #pragma unroll
  for (int n = 0; n < 8; ++n) {
    const int gwr = (n >> 1) * 512 + col0 + ((n & 1) * 16) + l15;
    const float b256 = (biq[gwr] + bhq[gwr]) * 256.0f;
    #pragma unroll
    for (int m = 0; m < 4; ++m) {
      acc[m][n][0] = b256; acc[m][n][1] = b256;
      acc[m][n][2] = b256; acc[m][n][3] = b256;
    }
  }

  #define STAGE_A(Asrc, kkv, dst)                                             \
    {                                                                         \
      _Pragma("unroll")                                                       \
      for (int i2 = 0; i2 < 8; ++i2)                                          \
        gload16((Asrc) + ainv[i2] + (kkv),                                    \
                (char*)&sA[dst][0] + (wid * 8 + i2) * 1024);                  \
    }
  #define STAGE_W(Wsrc, kkv)                                                  \
    {                                                                         \
      _Pragma("unroll")                                                       \
      for (int i2 = 0; i2 < 4; ++i2)                                          \
        gload16((Wsrc) + winv[i2] + (kkv),                                    \
                (char*)sW + (wid * 4 + i2) * 1024);                           \
    }
  // cprev tile (256 rows x 32 f32 cols = 32 KB) -> sA[0], linear layout:
  // float idx = r*32 + c. Wave stages exactly the rows its epilogue reads.
  #define STAGE_C                                                             \
    {                                                                         \
      _Pragma("unroll")                                                       \
      for (int i2 = 0; i2 < 8; ++i2) {                                        \
        const int c = wid * 8 + i2;                                           \
        const int r = c * 8 + (lane >> 3);                                    \
        gload16(cprev + (row0 + r) * 512 + col0 + ((lane & 7) << 2),          \
                (char*)&sA[0][0] + c * 1024);                                 \
      }                                                                       \
    }
  #define COMPUTE(cur)                                                        \
    {                                                                         \
      _Pragma("unroll")                                                       \
      for (int ks = 0; ks < 2; ++ks) {                                        \
        const int kb = ks * 4 + l4;                                           \
        half8 av[4];                                                          \
        _Pragma("unroll")                                                     \
        for (int m = 0; m < 4; ++m) {                                         \
          const int r = wid * 64 + m * 16 + l15;                              \
          av[m] = *(const half8*)&sA[cur][r * 64 + ((kb ^ (r & 7)) << 3)];    \
        }                                                                     \
        half8 bv[8];                                                          \
        _Pragma("unroll")                                                     \
        for (int n = 0; n < 8; ++n) {                                         \
          const int wr = n * 16 + l15;                                        \
          bv[n] = *(const half8*)&sW[wr * 64 + ((kb ^ (wr & 7)) << 3)];       \
        }                                                                     \
        __builtin_amdgcn_s_setprio(1);                                        \
        _Pragma("unroll")                                                     \
        for (int n = 0; n < 8; ++n)                                           \
          _Pragma("unroll")                                                   \
          for (int m = 0; m < 4; ++m)                                         \
            acc[m][n] = __builtin_amdgcn_mfma_f32_16x16x32_f16(               \
                av[m], bv[n], acc[m][n], 0, 0, 0);                            \
        __builtin_amdgcn_s_setprio(0);                                        \
      }                                                                       \
    }

  // ITER(T), T<15: W(T) DMA; A(T+1) DMA into buf (T+1)&1; vmcnt(8) [A(T),W(T)
  // done, A(T+1) in flight]; barrier; compute on buf T&1; barrier.
  #define ITER(T)                                                             \
    {                                                                         \
      { const __half* Wp_ = ((T) < 8) ? wiq : whq;                            \
        STAGE_W(Wp_, ((T) & 7) * 64) }                                        \
      {                                                                       \
        const __half* An_ = (((T) + 1) < 8) ? xq : hq;                        \
        STAGE_A(An_, (((T) + 1) & 7) * 64, ((T) + 1) & 1)                     \
      }                                                                       \
      asm volatile("s_waitcnt vmcnt(8)" ::: "memory");                        \
      __builtin_amdgcn_sched_barrier(0);                                      \
      __builtin_amdgcn_s_barrier();                                           \
      COMPUTE((T) & 1)                                                        \
      __builtin_amdgcn_s_barrier();                                           \
    }

  // prologue: A(0) -> sA[0] (completed at ITER(0)'s vmcnt)
  STAGE_A(xq, 0, 0)

  ITER(0)  ITER(1)  ITER(2)  ITER(3)
  ITER(4)  ITER(5)  ITER(6)  ITER(7)
  ITER(8)  ITER(9)  ITER(10) ITER(11)
  ITER(12) ITER(13) ITER(14)

  // ITER(15): last K-step; sA[0] is dead (last read in ITER(14)) -> stage
  // cprev into it, overlapped with W(15). All DMA drained at vmcnt(0); each
  // wave's epilogue reads only its own-staged rows (no extra barrier needed).
  {
    STAGE_W(whq, 7 * 64)
    STAGE_C
    asm volatile("s_waitcnt vmcnt(0)" ::: "memory");
    __builtin_amdgcn_sched_barrier(0);
    __builtin_amdgcn_s_barrier();
    COMPUTE(1)
  }

  #undef ITER
  #undef COMPUTE
  #undef STAGE_A
  #undef STAGE_W
  #undef STAGE_C

  // ---- final epilogue: s = rint(acc/256); gates -> c, h ----
  const float* sCp = (const float*)&sA[0][0];
  #pragma unroll
  for (int m = 0; m < 4; ++m)
    #pragma unroll
    for (int cb = 0; cb < 2; ++cb)
      #pragma unroll
      for (int j = 0; j < 4; ++j) {
        float s[4];
        #pragma unroll
        for (int g = 0; g < 4; ++g) {
          const int n = g * 2 + cb;
          s[g] = rintf(acc[m][n][j] * (1.0f / 256.0f));  // pre-act * 256 (int)
        }
        float vi, vf, vo, gg;
        {
          float t0 = (s[0] * (1.0f / 256.0f)) / 6.0f + 0.5f;
          vi = rintf(fminf(fmaxf(t0, 0.0f), 1.0f) * 256.0f);
        }
        {
          float t1 = (s[1] * (1.0f / 256.0f)) / 6.0f + 0.5f;
          vf = rintf(fminf(fmaxf(t1, 0.0f), 1.0f) * 256.0f);
        }
        gg = fminf(fmaxf(s[2], -256.f), 256.f);  // hard_tanh + quant == clip
        {
          float t3 = (s[3] * (1.0f / 256.0f)) / 6.0f + 0.5f;
          vo = rintf(fminf(fmaxf(t3, 0.0f), 1.0f) * 256.0f);
        }
        const int rloc = wid * 64 + m * 16 + l4 * 4 + j;
        const int R = row0 + rloc;
        const int C = col0 + cb * 16 + l15;
        const float cpq = quant256(sCp[rloc * 32 + cb * 16 + l15]);
        const float cnum = vf * cpq + vi * gg;       // exact int, scale 2^16
        const float cval = cnum * (1.0f / 65536.0f);
        out_c[R * 512 + C] = cval;
        const float tt = fminf(fmaxf(cval, -1.0f), 1.0f);
        const float th = rintf(tt * 256.0f);
        out_h[R * 512 + C] = (vo * th) * (1.0f / 65536.0f);
      }
}

extern "C" void kernel_launch(void* const* d_in, const int* in_sizes, int n_in,
                              void* d_out, int out_size, void* d_ws, size_t ws_size,
                              hipStream_t stream) {
  const float* x      = (const float*)d_in[0];
  const float* h_prev = (const float*)d_in[1];
  const float* c_prev = (const float*)d_in[2];
  const float* W_ih   = (const float*)d_in[3];
  const float* b_ih   = (const float*)d_in[4];
  const float* W_hh   = (const float*)d_in[5];
  const float* b_hh   = (const float*)d_in[6];
  float* out = (float*)d_out;

  char* ws = (char*)d_ws;
  __half* xqp  = (__half*)(ws);
  __half* hqp  = (__half*)(ws + (16u << 20));
  __half* wiqp = (__half*)(ws + (32u << 20));
  __half* whqp = (__half*)(ws + (34u << 20));
  float*  biqp = (float*)(ws + (36u << 20));
  float*  bhqp = (float*)(ws + (36u << 20) + 8192);

  prep_kernel<<<8192, 256, 0, stream>>>(x, h_prev, W_ih, W_hh, b_ih, b_hh,
                                        xqp, hqp, wiqp, whqp, biqp, bhqp);

  lstm_gemm<<<1024, 256, 0, stream>>>(xqp, hqp, wiqp, whqp, biqp, bhqp,
                                      c_prev, out, out + 8388608);
}

// Round 16
// 88.697 us; speedup vs baseline: 1.1059x; 1.0145x over previous
//
#include <hip/hip_runtime.h>
#include <hip/hip_fp16.h>

// FixedPointLSTMCell on MI355X — R16 (final): restore R13, the session best
// (87.5us, absmax 0.031 < 0.094 thr, 0 spill, 0 bank conflicts).
// Findings log: R14 (32x32 MFMA core) regressed -10.6us — 32-lane/32-row
// fragment reads are 4-way bank-conflicted at row-stride 128B (6.29M conflict
// cycles). R15 (cprev LDS prefetch) was null — epilogue tail latency already
// hidden by the sibling block. R5/R6/R11 deep pipelines all spilled or
// stalled: acc[4][8]=128 AGPRs leaves no register headroom for pipeline
// state at the mandatory 2-blocks/CU occupancy.
// Structure: A double-buffered LDS (2x32KB) via global_load_lds issued one
// K-step ahead; W single 16KB buffer; counted vmcnt(8) (A(t+1) stays in
// flight across compute); raw s_barrier pair per iter; 16-tile superloop
// spans both GEMMs. XOR-swizzled LDS (both sides), XCD-aware block swizzle.
// Numerics: all fake_quant'd operands are integers at scale 2^8; f16 MFMA on
// scaled ints is exact (fp32 accum < 2^24); both biases folded into the acc
// seed; single rounding s = rint(acc/256) (<=1 LSB vs ref's two roundings;
// propagated <=~0.035 vs 0.094 harness threshold).

typedef _Float16 half8 __attribute__((ext_vector_type(8)));
typedef float f32x4 __attribute__((ext_vector_type(4)));

#define AS1 __attribute__((address_space(1)))
#define AS3 __attribute__((address_space(3)))

__device__ __forceinline__ void gload16(const void* g, void* l) {
  __builtin_amdgcn_global_load_lds((const AS1 void*)g, (AS3 void*)l, 16, 0, 0);
}

__device__ __forceinline__ float quant256(float v) {
  float q = rintf(v * 256.0f);
  return fminf(fmaxf(q, -32767.0f), 32767.0f);
}

// ---------------- prep: quantize inputs to integer-valued fp16 ----------------
__global__ __launch_bounds__(256) void prep_kernel(
    const float* __restrict__ x, const float* __restrict__ h,
    const float* __restrict__ Wi, const float* __restrict__ Wh,
    const float* __restrict__ bi, const float* __restrict__ bh,
    __half* __restrict__ xq, __half* __restrict__ hq,
    __half* __restrict__ wiq, __half* __restrict__ whq,
    float* __restrict__ biq, float* __restrict__ bhq) {
  const int i = blockIdx.x * 256 + threadIdx.x;  // 4 elems each
  {
    const float4 vx = ((const float4*)x)[i];
    const float4 vh = ((const float4*)h)[i];
    union { __half hh[4]; uint2 u; } ux, uh;
    ux.hh[0] = __half(quant256(vx.x)); ux.hh[1] = __half(quant256(vx.y));
    ux.hh[2] = __half(quant256(vx.z)); ux.hh[3] = __half(quant256(vx.w));
    uh.hh[0] = __half(quant256(vh.x)); uh.hh[1] = __half(quant256(vh.y));
    uh.hh[2] = __half(quant256(vh.z)); uh.hh[3] = __half(quant256(vh.w));
    ((uint2*)xq)[i] = ux.u;
    ((uint2*)hq)[i] = uh.u;
  }
  if (i < 262144) {  // weights: 2048*512/4
    const float4 vi4 = ((const float4*)Wi)[i];
    const float4 vh4 = ((const float4*)Wh)[i];
    union { __half hh[4]; uint2 u; } uwi, uwh;
    uwi.hh[0] = __half(quant256(vi4.x)); uwi.hh[1] = __half(quant256(vi4.y));
    uwi.hh[2] = __half(quant256(vi4.z)); uwi.hh[3] = __half(quant256(vi4.w));
    uwh.hh[0] = __half(quant256(vh4.x)); uwh.hh[1] = __half(quant256(vh4.y));
    uwh.hh[2] = __half(quant256(vh4.z)); uwh.hh[3] = __half(quant256(vh4.w));
    ((uint2*)wiq)[i] = uwi.u;
    ((uint2*)whq)[i] = uwh.u;
  }
  if (i < 512) {  // biases (scaled-int, as float)
    #pragma unroll
    for (int j = 0; j < 4; ++j) {
      biq[i * 4 + j] = quant256(bi[i * 4 + j]);
      bhq[i * 4 + j] = quant256(bh[i * 4 + j]);
    }
  }
}

// ---------------- two-phase gate-fused GEMM + LSTM cell ----------------
// Block: 256 threads (4 waves), BM=256 rows, col-tile = 32 h-cols x 4 gates
// (128 gate-major wrows). Wave wid: rows [wid*64,+64), m=4; n=8 frags span
// all 128 wrows (frag n = gate n>>1, col (n&1)*16+l15) -> fused epilogue.
// Superloop T=0..15: tiles 0-7 X@Wi^T, 8-15 H@Wh^T (single acc, both biases
// pre-seeded). Per ITER: [W(T) DMA][A(T+1) DMA][vmcnt(8)][bar][64 MFMA][bar].
__global__ __launch_bounds__(256, 2) void lstm_gemm(
    const __half* __restrict__ xq, const __half* __restrict__ hq,
    const __half* __restrict__ wiq, const __half* __restrict__ whq,
    const float* __restrict__ biq, const float* __restrict__ bhq,
    const float* __restrict__ cprev,
    float* __restrict__ out_h, float* __restrict__ out_c) {
  __shared__ __align__(16) __half sA[2][256 * 64];  // 64 KB (A dbuf)
  __shared__ __align__(16) __half sW[128 * 64];     // 16 KB (W single)

  const int tid = threadIdx.x;
  const int lane = tid & 63;
  const int wid = tid >> 6;     // 0..3: 64-row slab
  const int l15 = lane & 15;
  const int l4 = lane >> 4;

  // XCD-aware bijective swizzle (1024 % 8 == 0)
  const int bid = blockIdx.x;
  const int lbid = (bid & 7) * 128 + (bid >> 3);
  const int tileM = lbid >> 4;  // 0..63
  const int tileN = lbid & 15;  // 0..15
  const int row0 = tileM * 256;
  const int col0 = tileN * 32;

  f32x4 acc[4][8];

  // hoisted loop-invariant staging offsets (element units; only kk varies)
  int ainv[8], winv[4];
  {
    const int b = lane & 7;
    const int lr = lane >> 3;
    #pragma unroll
    for (int i2 = 0; i2 < 8; ++i2) {
      const int r = (wid * 8 + i2) * 8 + lr;
      ainv[i2] = (row0 + r) * 512 + ((b ^ (r & 7)) << 3);
    }
    #pragma unroll
    for (int i2 = 0; i2 < 4; ++i2) {
      const int r = (wid * 4 + i2) * 8 + lr;
      const int gr = (r >> 5) * 512 + col0 + (r & 31);  // gate-major wrow
      winv[i2] = gr * 512 + ((b ^ (r & 7)) << 3);
    }
  }

  // seed acc with (bi + bh)*256 — both biases folded before single rounding
  #pragma unroll
  for (int n = 0; n < 8; ++n) {
    const int gwr = (n >> 1) * 512 + col0 + ((n & 1) * 16) + l15;
    const float b256 = (biq[gwr] + bhq[gwr]) * 256.0f;
    #pragma unroll
    for (int m = 0; m < 4; ++m) {
      acc[m][n][0] = b256; acc[m][n][1] = b256;
      acc[m][n][2] = b256; acc[m][n][3] = b256;
    }
  }

  #define STAGE_A(Asrc, kkv, dst)                                             \
    {                                                                         \
      _Pragma("unroll")                                                       \
      for (int i2 = 0; i2 < 8; ++i2)                                          \
        gload16((Asrc) + ainv[i2] + (kkv),                                    \
                (char*)&sA[dst][0] + (wid * 8 + i2) * 1024);                  \
    }
  #define STAGE_W(Wsrc, kkv)                                                  \
    {                                                                         \
      _Pragma("unroll")                                                       \
      for (int i2 = 0; i2 < 4; ++i2)                                          \
        gload16((Wsrc) + winv[i2] + (kkv),                                    \
                (char*)sW + (wid * 4 + i2) * 1024);                           \
    }
  #define COMPUTE(cur)                                                        \
    {                                                                         \
      _Pragma("unroll")                                                       \
      for (int ks = 0; ks < 2; ++ks) {                                        \
        const int kb = ks * 4 + l4;                                           \
        half8 av[4];                                                          \
        _Pragma("unroll")                                                     \
        for (int m = 0; m < 4; ++m) {                                         \
          const int r = wid * 64 + m * 16 + l15;                              \
          av[m] = *(const half8*)&sA[cur][r * 64 + ((kb ^ (r & 7)) << 3)];    \
        }                                                                     \
        half8 bv[8];                                                          \
        _Pragma("unroll")                                                     \
        for (int n = 0; n < 8; ++n) {                                         \
          const int wr = n * 16 + l15;                                        \
          bv[n] = *(const half8*)&sW[wr * 64 + ((kb ^ (wr & 7)) << 3)];       \
        }                                                                     \
        __builtin_amdgcn_s_setprio(1);                                        \
        _Pragma("unroll")                                                     \
        for (int n = 0; n < 8; ++n)                                           \
          _Pragma("unroll")                                                   \
          for (int m = 0; m < 4; ++m)                                         \
            acc[m][n] = __builtin_amdgcn_mfma_f32_16x16x32_f16(               \
                av[m], bv[n], acc[m][n], 0, 0, 0);                            \
        __builtin_amdgcn_s_setprio(0);                                        \
      }                                                                       \
    }

  // ITER(T): W(T) DMA; A(T+1) DMA into buf (T+1)&1; vmcnt(8) [A(T),W(T) done,
  // A(T+1) in flight]; barrier; compute on buf T&1; barrier.
  #define ITER(T)                                                             \
    {                                                                         \
      { const __half* Wp_ = ((T) < 8) ? wiq : whq;                            \
        STAGE_W(Wp_, ((T) & 7) * 64) }                                        \
      if ((T) < 15) {                                                         \
        const __half* An_ = (((T) + 1) < 8) ? xq : hq;                        \
        STAGE_A(An_, (((T) + 1) & 7) * 64, ((T) + 1) & 1)                     \
      }                                                                       \
      if ((T) < 15) { asm volatile("s_waitcnt vmcnt(8)" ::: "memory"); }      \
      else          { asm volatile("s_waitcnt vmcnt(0)" ::: "memory"); }      \
      __builtin_amdgcn_sched_barrier(0);                                      \
      __builtin_amdgcn_s_barrier();                                           \
      COMPUTE((T) & 1)                                                        \
      __builtin_amdgcn_s_barrier();                                           \
    }

  // prologue: A(0) -> sA[0] (completed at ITER(0)'s vmcnt)
  STAGE_A(xq, 0, 0)

  ITER(0)  ITER(1)  ITER(2)  ITER(3)
  ITER(4)  ITER(5)  ITER(6)  ITER(7)
  ITER(8)  ITER(9)  ITER(10) ITER(11)
  ITER(12) ITER(13) ITER(14) ITER(15)

  #undef ITER
  #undef COMPUTE
  #undef STAGE_A
  #undef STAGE_W

  // ---- final epilogue: s = rint(acc/256); gates -> c, h ----
  #pragma unroll
  for (int m = 0; m < 4; ++m)
    #pragma unroll
    for (int cb = 0; cb < 2; ++cb)
      #pragma unroll
      for (int j = 0; j < 4; ++j) {
        float s[4];
        #pragma unroll
        for (int g = 0; g < 4; ++g) {
          const int n = g * 2 + cb;
          s[g] = rintf(acc[m][n][j] * (1.0f / 256.0f));  // pre-act * 256 (int)
        }
        float vi, vf, vo, gg;
        {
          float t0 = (s[0] * (1.0f / 256.0f)) / 6.0f + 0.5f;
          vi = rintf(fminf(fmaxf(t0, 0.0f), 1.0f) * 256.0f);
        }
        {
          float t1 = (s[1] * (1.0f / 256.0f)) / 6.0f + 0.5f;
          vf = rintf(fminf(fmaxf(t1, 0.0f), 1.0f) * 256.0f);
        }
        gg = fminf(fmaxf(s[2], -256.f), 256.f);  // hard_tanh + quant == clip
        {
          float t3 = (s[3] * (1.0f / 256.0f)) / 6.0f + 0.5f;
          vo = rintf(fminf(fmaxf(t3, 0.0f), 1.0f) * 256.0f);
        }
        const int R = row0 + wid * 64 + m * 16 + l4 * 4 + j;
        const int C = col0 + cb * 16 + l15;
        const float cpq = quant256(cprev[R * 512 + C]);
        const float cnum = vf * cpq + vi * gg;       // exact int, scale 2^16
        const float cval = cnum * (1.0f / 65536.0f);
        out_c[R * 512 + C] = cval;
        const float tt = fminf(fmaxf(cval, -1.0f), 1.0f);
        const float th = rintf(tt * 256.0f);
        out_h[R * 512 + C] = (vo * th) * (1.0f / 65536.0f);
      }
}

extern "C" void kernel_launch(void* const* d_in, const int* in_sizes, int n_in,
                              void* d_out, int out_size, void* d_ws, size_t ws_size,
                              hipStream_t stream) {
  const float* x      = (const float*)d_in[0];
  const float* h_prev = (const float*)d_in[1];
  const float* c_prev = (const float*)d_in[2];
  const float* W_ih   = (const float*)d_in[3];
  const float* b_ih   = (const float*)d_in[4];
  const float* W_hh   = (const float*)d_in[5];
  const float* b_hh   = (const float*)d_in[6];
  float* out = (float*)d_out;

  char* ws = (char*)d_ws;
  __half* xqp  = (__half*)(ws);
  __half* hqp  = (__half*)(ws + (16u << 20));
  __half* wiqp = (__half*)(ws + (32u << 20));
  __half* whqp = (__half*)(ws + (34u << 20));
  float*  biqp = (float*)(ws + (36u << 20));
  float*  bhqp = (float*)(ws + (36u << 20) + 8192);

  prep_kernel<<<8192, 256, 0, stream>>>(x, h_prev, W_ih, W_hh, b_ih, b_hh,
                                        xqp, hqp, wiqp, whqp, biqp, bhqp);

  lstm_gemm<<<1024, 256, 0, stream>>>(xqp, hqp, wiqp, whqp, biqp, bhqp,
                                      c_prev, out, out + 8388608);
}